// Round 2
// 107.999 us; speedup vs baseline: 1.0139x; 1.0139x over previous
//
#include <hip/hip_runtime.h>
#include <math.h>

#define NCTRL 9
#define DIM 12           // NCTRL + 3
#define OUT_H 512
#define OUT_W 512
#define BATCH 32

// Native clang vector type — required by __builtin_nontemporal_store
// (HIP's float4 is a class and is rejected by the builtin).
typedef float nfloat4 __attribute__((ext_vector_type(4)));

// ---------------------------------------------------------------------------
// Kernel 1: per-batch TPS coefficient solve, REGISTER-RESIDENT.
// L v = [Q; 0]  with  L = [[K, P], [P^T, 0]],  K_ij = d2*log(d2), d2==0 -> 0.
//
// Rewrite rationale: previous version did Gauss-Jordan through fp64 LDS with
// 4 __syncthreads x 12 iterations and ~3 dependent 120-cy LDS round-trips
// per iteration, 1 wave/block -> pure latency chain, est. 15-40 us.
// New scheme: row-per-lane in VGPRs. Lanes (g*16 + r), r in 0..11, each own
// one 14-double augmented row (12 cols + 2 RHS). 4 batches per wave
// (aligned 16-lane groups so __shfl_xor with off<16 stays in-group).
// Partial pivoting WITHOUT row swaps: per step k, butterfly-argmax of
// |M[k]| over undone rows, broadcast pivot row via __shfl from the
// (group-uniform) pivot lane, eliminate in-register. Each lane records the
// column it pivoted (mycol) and the pivot diagonal; at the end
// x_{mycol} = RHS/pivdiag. Zero LDS, zero barriers, all indices
// compile-time (k-loop fully unrolled) so M[] stays in registers.
// Output coef layout per batch: WX[9], WY[9], AX[3], AY[3]  (24 floats).
// grid = BATCH/4 = 8 blocks, block = 64 (one wave).
// ---------------------------------------------------------------------------
__global__ __launch_bounds__(64) void tps_solve_kernel(
    const float* __restrict__ theta, float* __restrict__ coef) {
    const int lane = threadIdx.x;   // 0..63, single wave
    const int g = lane >> 4;        // 16-lane group -> batch within block
    const int r = lane & 15;        // row index; rows 12..15 inactive
    const int b = blockIdx.x * 4 + g;
    const float* th = theta + b * 36;  // QX[0:9] QY[9:18] PX[18:27] PY[27:36]

    const bool arow = (r < DIM);

    double M[14];
    double pxr = 0.0, pyr = 0.0;
    if (r < NCTRL) { pxr = (double)th[18 + r]; pyr = (double)th[27 + r]; }

    // Build my augmented row. K block has ILP across the 9 fp64 logs.
    #pragma unroll
    for (int c = 0; c < NCTRL; ++c) {
        const double pxc = (double)th[18 + c];
        const double pyc = (double)th[27 + c];
        double v = 0.0;
        if (r < NCTRL) {
            const double dx = pxr - pxc;
            const double dy = pyr - pyc;
            const double d2 = dx * dx + dy * dy;
            // ref: d2==0 -> 1.0 -> 1*log(1) = 0
            v = (d2 == 0.0) ? 0.0 : d2 * log(d2);
        } else if (r == 9)  v = 1.0;    // P^T row: ones
        else if (r == 10)   v = pxc;    // P^T row: PX
        else if (r == 11)   v = pyc;    // P^T row: PY
        M[c] = v;
    }
    if (r < NCTRL) {
        M[9] = 1.0; M[10] = pxr; M[11] = pyr;   // P block
        M[12] = (double)th[r];                  // RHS x: QX
        M[13] = (double)th[NCTRL + r];          // RHS y: QY
    } else {
        M[9] = 0.0; M[10] = 0.0; M[11] = 0.0;   // Z block
        M[12] = 0.0; M[13] = 0.0;               // RHS zeros
    }

    bool done = false;
    int mycol = -1;
    double pivdiag = 1.0;

    #pragma unroll
    for (int k = 0; k < DIM; ++k) {
        // Argmax |M[k]| over undone active rows; butterfly within 16-group.
        // Inactive/done lanes post -1 (always lose: fabs >= 0 > -1).
        double mv = (arow && !done) ? fabs(M[k]) : -1.0;
        int mi = r;
        #pragma unroll
        for (int off = 8; off > 0; off >>= 1) {
            const double ov = __shfl_xor(mv, off);
            const int oi = __shfl_xor(mi, off);
            if (ov > mv || (ov == mv && oi < mi)) { mv = ov; mi = oi; }
        }
        // mi is group-uniform (index-tiebreak makes the butterfly consistent)
        const int src = (g << 4) | mi;
        const double pkk = __shfl(M[k], src);
        const double rp = 1.0 / pkk;
        const double f = M[k] * rp;     // my elimination factor (reads pre-update M[k])
        const bool ispiv = (r == mi);
        if (ispiv) { done = true; mycol = k; pivdiag = pkk; }
        // Eliminate column k from every other row. Columns <= k are never
        // read again, so skip storing them. Gauss-Jordan invariant: a done
        // row's own pivot column is untouched (c >= k+1 > its column).
        #pragma unroll
        for (int c = k + 1; c < 14; ++c) {
            const double Pc = __shfl(M[c], src);
            if (!ispiv) M[c] -= f * Pc;
        }
    }

    if (mycol >= 0) {
        // My row ended as: pivdiag * x_{mycol} = RHS (all other pivot
        // columns eliminated). pivdiag saved at pivot time == final M[mycol].
        const double inv = 1.0 / pivdiag;
        const float x = (float)(M[12] * inv);
        const float y = (float)(M[13] * inv);
        float* cb = coef + b * 24;
        if (mycol < NCTRL) {
            cb[mycol] = x;               // WX
            cb[9 + mycol] = y;           // WY
        } else {
            cb[18 + (mycol - 9)] = x;    // AX
            cb[21 + (mycol - 9)] = y;    // AY
        }
    }
}

// ---------------------------------------------------------------------------
// Kernel 2: grid evaluation. 8 pixels per thread arranged as 2 cols x 4 ROWS:
// thread t covers cols (2t, 2t+1) of 4 consecutive rows. Each of the 4
// 16B nontemporal stores is lane-CONTIGUOUS (lane stride 16B -> wave writes
// 1KiB, block writes a full 4KiB row per instruction). Round-4 lesson: 8
// ADJACENT pixels/thread made lane stride 64B per store instruction ->
// partial-line nt writes -> WRITE_SIZE 2.3x amplification (152MB vs 67MB).
// grid = (H/4, BATCH) = (128, 32), block = 256.   [UNCHANGED — at write
// roofline: 64 MiB nt-stores ~= 10.6 us @ 6.3 TB/s, VALU/log overlap it.]
// ---------------------------------------------------------------------------
__global__ __launch_bounds__(256) void tps_grid_kernel(
    const float* __restrict__ theta, const float* __restrict__ coef,
    float* __restrict__ out) {
    const int b = blockIdx.y;
    const float* th = theta + b * 36;
    const float* cf = coef + b * 24;

    // Uniform (scalar) loads of per-batch params
    float PX[NCTRL], PY[NCTRL], WX[NCTRL], WY[NCTRL];
    #pragma unroll
    for (int n = 0; n < NCTRL; ++n) {
        PX[n] = th[18 + n];
        PY[n] = th[27 + n];
        WX[n] = cf[n];
        WY[n] = cf[9 + n];
    }
    const float AX0 = cf[18], AX1 = cf[19], AX2 = cf[20];
    const float AY0 = cf[21], AY1 = cf[22], AY2 = cf[23];

    const int t = threadIdx.x;
    const int row0 = blockIdx.x * 4;       // first of 4 consecutive rows
    const int col0 = t * 2;                // this thread's column pair

    const float step = 2.0f / 511.0f;
    const float gx0 = -1.0f + step * (float)col0;
    const float gx1 = gx0 + step;
    const float gy0 = -1.0f + step * (float)row0;

    float xp[8], yp[8];                    // [row q][col i] at index q*2+i
    #pragma unroll
    for (int q = 0; q < 4; ++q) {
        const float gy = gy0 + step * (float)q;
        xp[q * 2 + 0] = AX0 + AX1 * gx0 + AX2 * gy;
        yp[q * 2 + 0] = AY0 + AY1 * gx0 + AY2 * gy;
        xp[q * 2 + 1] = AX0 + AX1 * gx1 + AX2 * gy;
        yp[q * 2 + 1] = AY0 + AY1 * gx1 + AY2 * gy;
    }

    #pragma unroll
    for (int n = 0; n < NCTRL; ++n) {
        const float dx0 = gx0 - PX[n];
        const float dx1 = dx0 + step;
        const float dx0sq = dx0 * dx0;
        const float dx1sq = dx1 * dx1;
        float dy = gy0 - PY[n];
        #pragma unroll
        for (int q = 0; q < 4; ++q) {
            const float r20 = __builtin_fmaf(dy, dy, dx0sq);
            const float r21 = __builtin_fmaf(dy, dy, dx1sq);
            // r2==0 -> u = 0 * log(1e-30) = -0.f == ref's 0 (d2->1, log1=0)
            const float u0 = r20 * __logf(fmaxf(r20, 1e-30f));
            const float u1 = r21 * __logf(fmaxf(r21, 1e-30f));
            xp[q * 2 + 0] = __builtin_fmaf(u0, WX[n], xp[q * 2 + 0]);
            yp[q * 2 + 0] = __builtin_fmaf(u0, WY[n], yp[q * 2 + 0]);
            xp[q * 2 + 1] = __builtin_fmaf(u1, WX[n], xp[q * 2 + 1]);
            yp[q * 2 + 1] = __builtin_fmaf(u1, WY[n], yp[q * 2 + 1]);
            dy += step;
        }
    }

    #pragma unroll
    for (int q = 0; q < 4; ++q) {
        const size_t off =
            (((size_t)b * OUT_H + (size_t)(row0 + q)) * OUT_W + (size_t)col0) * 2;
        nfloat4 o = {xp[q * 2], yp[q * 2], xp[q * 2 + 1], yp[q * 2 + 1]};
        __builtin_nontemporal_store(o, (nfloat4*)(out + off));
    }
}

extern "C" void kernel_launch(void* const* d_in, const int* in_sizes, int n_in,
                              void* d_out, int out_size, void* d_ws, size_t ws_size,
                              hipStream_t stream) {
    const float* theta = (const float*)d_in[0];
    float* out = (float*)d_out;
    float* coef = (float*)d_ws;  // 32 * 24 floats = 3 KiB

    tps_solve_kernel<<<dim3(BATCH / 4), dim3(64), 0, stream>>>(theta, coef);

    tps_grid_kernel<<<dim3(OUT_H / 4, BATCH), dim3(256), 0, stream>>>(theta, coef, out);
}